// Round 4
// baseline (817.361 us; speedup 1.0000x reference)
//
#include <hip/hip_runtime.h>
#include <hip/hip_bf16.h>
#include <stdint.h>

typedef __attribute__((ext_vector_type(8))) short bf16x8;
typedef __attribute__((ext_vector_type(4))) float f32x4;

typedef const __attribute__((address_space(1))) void* gas_ptr;
typedef __attribute__((address_space(3))) void* lds_ptr_t;

__device__ __forceinline__ unsigned short f32_to_bf16_rtn(float x) {
    unsigned u = __float_as_uint(x);
    u += 0x7FFFu + ((u >> 16) & 1u);
    return (unsigned short)(u >> 16);
}
__device__ __forceinline__ float bf16_bits_to_f32(unsigned short h) {
    return __uint_as_float(((unsigned)h) << 16);
}

// ---------------------------------------------------------------------------
// Kernel 1: split fp32 inputs into hi/lo bf16 pairs (a = hi + lo, err ~2^-17)
// ---------------------------------------------------------------------------
__global__ __launch_bounds__(256) void split_hi_lo(
    const float* __restrict__ A, const float* __restrict__ B,
    unsigned short* __restrict__ Ahi, unsigned short* __restrict__ Alo,
    unsigned short* __restrict__ Bhi, unsigned short* __restrict__ Blo, int n4)
{
    int i = blockIdx.x * 256 + threadIdx.x;
    if (i >= n4) return;
    float4 a = ((const float4*)A)[i];
    float4 b = ((const float4*)B)[i];
    ushort4 h, l;

    h.x = f32_to_bf16_rtn(a.x); l.x = f32_to_bf16_rtn(a.x - bf16_bits_to_f32(h.x));
    h.y = f32_to_bf16_rtn(a.y); l.y = f32_to_bf16_rtn(a.y - bf16_bits_to_f32(h.y));
    h.z = f32_to_bf16_rtn(a.z); l.z = f32_to_bf16_rtn(a.z - bf16_bits_to_f32(h.z));
    h.w = f32_to_bf16_rtn(a.w); l.w = f32_to_bf16_rtn(a.w - bf16_bits_to_f32(h.w));
    ((ushort4*)Ahi)[i] = h; ((ushort4*)Alo)[i] = l;

    h.x = f32_to_bf16_rtn(b.x); l.x = f32_to_bf16_rtn(b.x - bf16_bits_to_f32(h.x));
    h.y = f32_to_bf16_rtn(b.y); l.y = f32_to_bf16_rtn(b.y - bf16_bits_to_f32(h.y));
    h.z = f32_to_bf16_rtn(b.z); l.z = f32_to_bf16_rtn(b.z - bf16_bits_to_f32(h.z));
    h.w = f32_to_bf16_rtn(b.w); l.w = f32_to_bf16_rtn(b.w - bf16_bits_to_f32(h.w));
    ((ushort4*)Bhi)[i] = h; ((ushort4*)Blo)[i] = l;
}

// ---------------------------------------------------------------------------
// Kernel 2 (presplit, hot path): energies = A @ B^T, split-bf16 3-product GEMM.
// r1 structure (16x16x32 mfma, 4x4 tiles/wave, 128x128 block, BK=32) with a
// register diet to reach 4 waves/SIMD (<=128 unified VGPR+AGPR):
//   - acc 64 + B-frags held live 32 + A-frags streamed per-i 8
//   - all 16 ds_reads share 2 address VGPRs + immediate offsets
//   - __launch_bounds__(256, 4) forces the allocator to 128
// XOR swizzle on 16B chunks retained (position p holds data chunk
// p ^ ((row>>1)&3)); applied on the global SOURCE side for global_load_lds.
// ---------------------------------------------------------------------------
__global__ __launch_bounds__(256, 4) void gemm_presplit(
    const __hip_bfloat16* __restrict__ Ahi, const __hip_bfloat16* __restrict__ Alo,
    const __hip_bfloat16* __restrict__ Bhi, const __hip_bfloat16* __restrict__ Blo,
    float* __restrict__ out, int M, int N, int K)
{
    __shared__ char sm[32768];   // [0,8K)=Ahi [8K,16K)=Alo [16K,24K)=Bhi [24K,32K)=Blo
    const int tid  = threadIdx.x;
    const int lane = tid & 63;
    const int w    = tid >> 6;
    const int bm = blockIdx.y, bn = blockIdx.x;
    const int wm = (w >> 1) * 64;
    const int wn = (w & 1) * 64;

    f32x4 acc[4][4] = {};

    // staging: thread owns LDS chunk (row=(c&1)*64 + tid>>2, pos=tid&3);
    // fetches source chunk (tid&3) ^ ((row>>1)&3) = (tid&3) ^ ((tid>>3)&3)
    const int sfetch = (tid & 3) ^ ((tid >> 3) & 3);
    const size_t offA = (size_t)(bm * 128 + (tid >> 2)) * K + sfetch * 8;
    const size_t offB = (size_t)(bn * 128 + (tid >> 2)) * K + sfetch * 8;
    const __hip_bfloat16* pAh = Ahi + offA;
    const __hip_bfloat16* pAl = Alo + offA;
    const __hip_bfloat16* pBh = Bhi + offB;
    const __hip_bfloat16* pBl = Blo + offB;
    const size_t half = (size_t)64 * K;   // +64 rows
    char* dst0 = sm + tid * 16;

    // read side: fragment chunk = lane>>4, swizzled: ^ ((lane>>1)&3)
    const int rA = lane & 15;
    const int ca = (lane >> 4) ^ ((lane >> 1) & 3);
    const char* aP = sm +         (wm + rA) * 64 + ca * 16;   // A-hi base
    const char* bP = sm + 16384 + (wn + rA) * 64 + ca * 16;   // B-hi base

    for (int k0 = 0; k0 < K; k0 += 32) {
        __syncthreads();
        __builtin_amdgcn_global_load_lds((gas_ptr)(pAh + k0),        (lds_ptr_t)(dst0),         16, 0, 0);
        __builtin_amdgcn_global_load_lds((gas_ptr)(pAh + half + k0), (lds_ptr_t)(dst0 + 4096),  16, 0, 0);
        __builtin_amdgcn_global_load_lds((gas_ptr)(pAl + k0),        (lds_ptr_t)(dst0 + 8192),  16, 0, 0);
        __builtin_amdgcn_global_load_lds((gas_ptr)(pAl + half + k0), (lds_ptr_t)(dst0 + 12288), 16, 0, 0);
        __builtin_amdgcn_global_load_lds((gas_ptr)(pBh + k0),        (lds_ptr_t)(dst0 + 16384), 16, 0, 0);
        __builtin_amdgcn_global_load_lds((gas_ptr)(pBh + half + k0), (lds_ptr_t)(dst0 + 20480), 16, 0, 0);
        __builtin_amdgcn_global_load_lds((gas_ptr)(pBl + k0),        (lds_ptr_t)(dst0 + 24576), 16, 0, 0);
        __builtin_amdgcn_global_load_lds((gas_ptr)(pBl + half + k0), (lds_ptr_t)(dst0 + 28672), 16, 0, 0);
        __syncthreads();

        // B fragments held live (32 VGPR); A streamed per-i (8 VGPR)
        bf16x8 bh[4], bl[4];
#pragma unroll
        for (int j = 0; j < 4; ++j) {
            bh[j] = *(const bf16x8*)(bP + j * 1024);
            bl[j] = *(const bf16x8*)(bP + j * 1024 + 8192);
        }
#pragma unroll
        for (int i = 0; i < 4; ++i) {
            bf16x8 ah = *(const bf16x8*)(aP + i * 1024);
            bf16x8 al = *(const bf16x8*)(aP + i * 1024 + 8192);
#pragma unroll
            for (int j = 0; j < 4; ++j) {
                acc[i][j] = __builtin_amdgcn_mfma_f32_16x16x32_bf16(ah, bh[j], acc[i][j], 0, 0, 0);
                acc[i][j] = __builtin_amdgcn_mfma_f32_16x16x32_bf16(al, bh[j], acc[i][j], 0, 0, 0);
                acc[i][j] = __builtin_amdgcn_mfma_f32_16x16x32_bf16(ah, bl[j], acc[i][j], 0, 0, 0);
            }
        }
    }

    // Epilogue: 16x16 C/D layout col=lane&15, row=(lane>>4)*4+reg (m89/m91)
    const int r0 = bm * 128 + wm + ((lane >> 4) << 2);
    const int c0 = bn * 128 + wn + rA;
#pragma unroll
    for (int i = 0; i < 4; ++i)
#pragma unroll
        for (int j = 0; j < 4; ++j)
#pragma unroll
            for (int r = 0; r < 4; ++r)
                out[(size_t)(r0 + i * 16 + r) * N + (c0 + j * 16)] = acc[i][j][r];
}

// ---------------------------------------------------------------------------
// Kernel 2b (fallback, ws too small — not expected to run): inline split.
// ---------------------------------------------------------------------------
__global__ __launch_bounds__(256) void gemm_fallback(
    const float* __restrict__ Af, const float* __restrict__ Bf,
    float* __restrict__ out, int M, int N, int K)
{
    __shared__ char sm[32768];
    const int tid  = threadIdx.x;
    const int lane = tid & 63;
    const int w    = tid >> 6;
    const int bm = blockIdx.y, bn = blockIdx.x;
    const int wm = (w >> 1) * 64;
    const int wn = (w & 1) * 64;

    f32x4 acc[4][4] = {};
    const int sfetch = (tid & 3) ^ ((tid >> 3) & 3);
    const int rA = lane & 15;
    const int ca = (lane >> 4) ^ ((lane >> 1) & 3);
    const char* aP = sm +         (wm + rA) * 64 + ca * 16;
    const char* bP = sm + 16384 + (wn + rA) * 64 + ca * 16;

    for (int k0 = 0; k0 < K; k0 += 32) {
        __syncthreads();
#pragma unroll
        for (int c = 0; c < 4; ++c) {
            const bool isA = (c < 2);
            const int row = ((c & 1) << 6) + (tid >> 2);
            const float* src = (isA ? Af + (size_t)(bm * 128 + row) * K
                                    : Bf + (size_t)(bn * 128 + row) * K)
                               + k0 + ((tid & 3) << 3);
            f32x4 v0 = *(const f32x4*)src;
            f32x4 v1 = *(const f32x4*)(src + 4);
            float vv[8] = {v0.x, v0.y, v0.z, v0.w, v1.x, v1.y, v1.z, v1.w};
            bf16x8 h, l;
#pragma unroll
            for (int j = 0; j < 8; ++j) {
                unsigned short hb = f32_to_bf16_rtn(vv[j]);
                unsigned short lb = f32_to_bf16_rtn(vv[j] - bf16_bits_to_f32(hb));
                h[j] = (short)hb; l[j] = (short)lb;
            }
            const int g = row * 64 + sfetch * 16;
            *(bf16x8*)(sm + (isA ? 0 : 16384) + g) = h;
            *(bf16x8*)(sm + (isA ? 8192 : 24576) + g) = l;
        }
        __syncthreads();

        bf16x8 bh[4], bl[4];
#pragma unroll
        for (int j = 0; j < 4; ++j) {
            bh[j] = *(const bf16x8*)(bP + j * 1024);
            bl[j] = *(const bf16x8*)(bP + j * 1024 + 8192);
        }
#pragma unroll
        for (int i = 0; i < 4; ++i) {
            bf16x8 ah = *(const bf16x8*)(aP + i * 1024);
            bf16x8 al = *(const bf16x8*)(aP + i * 1024 + 8192);
#pragma unroll
            for (int j = 0; j < 4; ++j) {
                acc[i][j] = __builtin_amdgcn_mfma_f32_16x16x32_bf16(ah, bh[j], acc[i][j], 0, 0, 0);
                acc[i][j] = __builtin_amdgcn_mfma_f32_16x16x32_bf16(al, bh[j], acc[i][j], 0, 0, 0);
                acc[i][j] = __builtin_amdgcn_mfma_f32_16x16x32_bf16(ah, bl[j], acc[i][j], 0, 0, 0);
            }
        }
    }

    const int r0 = bm * 128 + wm + ((lane >> 4) << 2);
    const int c0 = bn * 128 + wn + rA;
#pragma unroll
    for (int i = 0; i < 4; ++i)
#pragma unroll
        for (int j = 0; j < 4; ++j)
#pragma unroll
            for (int r = 0; r < 4; ++r)
                out[(size_t)(r0 + i * 16 + r) * N + (c0 + j * 16)] = acc[i][j][r];
}

// ---------------------------------------------------------------------------
// Kernel 3: in-place row softmax. One block (512 thr, 8 waves) per row;
// row of 8192 floats = 4 f32x4 per thread. NT final stores.
// ---------------------------------------------------------------------------
__global__ __launch_bounds__(512) void softmax_rows_8192(float* __restrict__ d)
{
    const int tid = threadIdx.x;
    f32x4* p = (f32x4*)(d + (size_t)blockIdx.x * 8192);
    f32x4 v[4];
    float m = -3.402823466e+38f;
#pragma unroll
    for (int i = 0; i < 4; ++i) {
        v[i] = p[tid + (i << 9)];
        m = fmaxf(m, fmaxf(fmaxf(v[i].x, v[i].y), fmaxf(v[i].z, v[i].w)));
    }
#pragma unroll
    for (int o = 32; o >= 1; o >>= 1) m = fmaxf(m, __shfl_xor(m, o));
    __shared__ float smax[8], ssum[8];
    if ((tid & 63) == 0) smax[tid >> 6] = m;
    __syncthreads();
#pragma unroll
    for (int q = 0; q < 8; ++q) m = fmaxf(m, smax[q]);

    float s = 0.f;
#pragma unroll
    for (int i = 0; i < 4; ++i) {
        v[i].x = __expf(v[i].x - m);
        v[i].y = __expf(v[i].y - m);
        v[i].z = __expf(v[i].z - m);
        v[i].w = __expf(v[i].w - m);
        s += (v[i].x + v[i].y) + (v[i].z + v[i].w);
    }
#pragma unroll
    for (int o = 32; o >= 1; o >>= 1) s += __shfl_xor(s, o);
    if ((tid & 63) == 0) ssum[tid >> 6] = s;
    __syncthreads();
    s = 0.f;
#pragma unroll
    for (int q = 0; q < 8; ++q) s += ssum[q];
    const float r = 1.0f / s;
#pragma unroll
    for (int i = 0; i < 4; ++i) {
        v[i] *= r;
        __builtin_nontemporal_store(v[i], &p[tid + (i << 9)]);
    }
}

// ---------------------------------------------------------------------------
extern "C" void kernel_launch(void* const* d_in, const int* in_sizes, int n_in,
                              void* d_out, int out_size, void* d_ws, size_t ws_size,
                              hipStream_t stream)
{
    const float* A = (const float*)d_in[0];   // user_emb [M, K] fp32
    const float* B = (const float*)d_in[1];   // id_emb   [N, K] fp32
    float* out = (float*)d_out;               // [M, N] fp32
    const int K = 1024;
    const int M = in_sizes[0] / K;
    const int N = in_sizes[1] / K;
    const size_t elemsA = (size_t)M * K;
    const size_t elemsB = (size_t)N * K;
    const size_t need = 2 * (elemsA + elemsB) * sizeof(unsigned short);

    dim3 grid(N / 128, M / 128);
    const bool presplit = (ws_size >= need) && (M == N);

    if (presplit) {
        unsigned short* Ahi = (unsigned short*)d_ws;
        unsigned short* Alo = Ahi + elemsA;
        unsigned short* Bhi = Alo + elemsA;
        unsigned short* Blo = Bhi + elemsB;
        const int n4 = (int)(elemsA / 4);
        split_hi_lo<<<(n4 + 255) / 256, 256, 0, stream>>>(A, B, Ahi, Alo, Bhi, Blo, n4);
        gemm_presplit<<<grid, 256, 0, stream>>>(
            (const __hip_bfloat16*)Ahi, (const __hip_bfloat16*)Alo,
            (const __hip_bfloat16*)Bhi, (const __hip_bfloat16*)Blo,
            out, M, N, K);
    } else {
        gemm_fallback<<<grid, 256, 0, stream>>>(A, B, out, M, N, K);
    }
    softmax_rows_8192<<<M, 512, 0, stream>>>(out);
}

// Round 5
// 739.098 us; speedup vs baseline: 1.1059x; 1.1059x over previous
//
#include <hip/hip_runtime.h>
#include <hip/hip_bf16.h>
#include <stdint.h>

typedef __attribute__((ext_vector_type(8))) short bf16x8;
typedef __attribute__((ext_vector_type(4))) float f32x4;

typedef const __attribute__((address_space(1))) void* gas_ptr;
typedef __attribute__((address_space(3))) void* lds_ptr_t;

__device__ __forceinline__ unsigned short f32_to_bf16_rtn(float x) {
    unsigned u = __float_as_uint(x);
    u += 0x7FFFu + ((u >> 16) & 1u);
    return (unsigned short)(u >> 16);
}
__device__ __forceinline__ float bf16_bits_to_f32(unsigned short h) {
    return __uint_as_float(((unsigned)h) << 16);
}

// ---------------------------------------------------------------------------
// Kernel 1: split fp32 inputs into hi/lo bf16 pairs (a = hi + lo, err ~2^-17)
// ---------------------------------------------------------------------------
__global__ __launch_bounds__(256) void split_hi_lo(
    const float* __restrict__ A, const float* __restrict__ B,
    unsigned short* __restrict__ Ahi, unsigned short* __restrict__ Alo,
    unsigned short* __restrict__ Bhi, unsigned short* __restrict__ Blo, int n4)
{
    int i = blockIdx.x * 256 + threadIdx.x;
    if (i >= n4) return;
    float4 a = ((const float4*)A)[i];
    float4 b = ((const float4*)B)[i];
    ushort4 h, l;

    h.x = f32_to_bf16_rtn(a.x); l.x = f32_to_bf16_rtn(a.x - bf16_bits_to_f32(h.x));
    h.y = f32_to_bf16_rtn(a.y); l.y = f32_to_bf16_rtn(a.y - bf16_bits_to_f32(h.y));
    h.z = f32_to_bf16_rtn(a.z); l.z = f32_to_bf16_rtn(a.z - bf16_bits_to_f32(h.z));
    h.w = f32_to_bf16_rtn(a.w); l.w = f32_to_bf16_rtn(a.w - bf16_bits_to_f32(h.w));
    ((ushort4*)Ahi)[i] = h; ((ushort4*)Alo)[i] = l;

    h.x = f32_to_bf16_rtn(b.x); l.x = f32_to_bf16_rtn(b.x - bf16_bits_to_f32(h.x));
    h.y = f32_to_bf16_rtn(b.y); l.y = f32_to_bf16_rtn(b.y - bf16_bits_to_f32(h.y));
    h.z = f32_to_bf16_rtn(b.z); l.z = f32_to_bf16_rtn(b.z - bf16_bits_to_f32(h.z));
    h.w = f32_to_bf16_rtn(b.w); l.w = f32_to_bf16_rtn(b.w - bf16_bits_to_f32(h.w));
    ((ushort4*)Bhi)[i] = h; ((ushort4*)Blo)[i] = l;
}

// ---------------------------------------------------------------------------
// Kernel 2 (presplit, hot path): energies = A @ B^T, split-bf16 3-product GEMM.
// 16x16x32 mfma, 4x4 tiles/wave, 128x128 block, BK=32.
// XOR swizzle on 16B chunks (position p holds data chunk p ^ ((row>>1)&3)):
// r4 measured SQ_LDS_BANK_CONFLICT == 0 with this exact pattern.
// NO min-waves launch bound: r4's (256,4) forced 128-reg budget -> ~330 MB of
// scratch spill stores in the K-loop (WRITE_SIZE 262->592 MB) and a 470 us
// regression. Natural allocation (~84-100 VGPR + 64 AGPR, 3 blocks/CU) wins.
// ---------------------------------------------------------------------------
__global__ __launch_bounds__(256) void gemm_presplit(
    const __hip_bfloat16* __restrict__ Ahi, const __hip_bfloat16* __restrict__ Alo,
    const __hip_bfloat16* __restrict__ Bhi, const __hip_bfloat16* __restrict__ Blo,
    float* __restrict__ out, int M, int N, int K)
{
    __shared__ char sm[32768];   // [0,8K)=Ahi [8K,16K)=Alo [16K,24K)=Bhi [24K,32K)=Blo
    const int tid  = threadIdx.x;
    const int lane = tid & 63;
    const int w    = tid >> 6;
    const int bm = blockIdx.y, bn = blockIdx.x;
    const int wm = (w >> 1) * 64;
    const int wn = (w & 1) * 64;

    f32x4 acc[4][4] = {};

    // staging: thread owns LDS chunk (row=(c&1)*64 + tid>>2, pos=tid&3);
    // fetches source chunk (tid&3) ^ ((row>>1)&3) = (tid&3) ^ ((tid>>3)&3)
    const int sfetch = (tid & 3) ^ ((tid >> 3) & 3);
    const size_t offA = (size_t)(bm * 128 + (tid >> 2)) * K + sfetch * 8;
    const size_t offB = (size_t)(bn * 128 + (tid >> 2)) * K + sfetch * 8;
    const __hip_bfloat16* pAh = Ahi + offA;
    const __hip_bfloat16* pAl = Alo + offA;
    const __hip_bfloat16* pBh = Bhi + offB;
    const __hip_bfloat16* pBl = Blo + offB;
    const size_t half = (size_t)64 * K;   // +64 rows
    char* dst0 = sm + tid * 16;

    // read side: fragment chunk = lane>>4, swizzled: ^ ((lane>>1)&3)
    const int rA = lane & 15;
    const int ca = (lane >> 4) ^ ((lane >> 1) & 3);
    const char* aP = sm +         (wm + rA) * 64 + ca * 16;   // A-hi base
    const char* bP = sm + 16384 + (wn + rA) * 64 + ca * 16;   // B-hi base

    for (int k0 = 0; k0 < K; k0 += 32) {
        __syncthreads();
        __builtin_amdgcn_global_load_lds((gas_ptr)(pAh + k0),        (lds_ptr_t)(dst0),         16, 0, 0);
        __builtin_amdgcn_global_load_lds((gas_ptr)(pAh + half + k0), (lds_ptr_t)(dst0 + 4096),  16, 0, 0);
        __builtin_amdgcn_global_load_lds((gas_ptr)(pAl + k0),        (lds_ptr_t)(dst0 + 8192),  16, 0, 0);
        __builtin_amdgcn_global_load_lds((gas_ptr)(pAl + half + k0), (lds_ptr_t)(dst0 + 12288), 16, 0, 0);
        __builtin_amdgcn_global_load_lds((gas_ptr)(pBh + k0),        (lds_ptr_t)(dst0 + 16384), 16, 0, 0);
        __builtin_amdgcn_global_load_lds((gas_ptr)(pBh + half + k0), (lds_ptr_t)(dst0 + 20480), 16, 0, 0);
        __builtin_amdgcn_global_load_lds((gas_ptr)(pBl + k0),        (lds_ptr_t)(dst0 + 24576), 16, 0, 0);
        __builtin_amdgcn_global_load_lds((gas_ptr)(pBl + half + k0), (lds_ptr_t)(dst0 + 28672), 16, 0, 0);
        __syncthreads();

        bf16x8 bh[4], bl[4];
#pragma unroll
        for (int j = 0; j < 4; ++j) {
            bh[j] = *(const bf16x8*)(bP + j * 1024);
            bl[j] = *(const bf16x8*)(bP + j * 1024 + 8192);
        }
#pragma unroll
        for (int i = 0; i < 4; ++i) {
            bf16x8 ah = *(const bf16x8*)(aP + i * 1024);
            bf16x8 al = *(const bf16x8*)(aP + i * 1024 + 8192);
#pragma unroll
            for (int j = 0; j < 4; ++j) {
                acc[i][j] = __builtin_amdgcn_mfma_f32_16x16x32_bf16(ah, bh[j], acc[i][j], 0, 0, 0);
                acc[i][j] = __builtin_amdgcn_mfma_f32_16x16x32_bf16(al, bh[j], acc[i][j], 0, 0, 0);
                acc[i][j] = __builtin_amdgcn_mfma_f32_16x16x32_bf16(ah, bl[j], acc[i][j], 0, 0, 0);
            }
        }
    }

    // Epilogue: 16x16 C/D layout col=lane&15, row=(lane>>4)*4+reg (m89/m91)
    const int r0 = bm * 128 + wm + ((lane >> 4) << 2);
    const int c0 = bn * 128 + wn + rA;
#pragma unroll
    for (int i = 0; i < 4; ++i)
#pragma unroll
        for (int j = 0; j < 4; ++j)
#pragma unroll
            for (int r = 0; r < 4; ++r)
                out[(size_t)(r0 + i * 16 + r) * N + (c0 + j * 16)] = acc[i][j][r];
}

// ---------------------------------------------------------------------------
// Kernel 2b (fallback, ws too small — not expected to run): inline split.
// ---------------------------------------------------------------------------
__global__ __launch_bounds__(256) void gemm_fallback(
    const float* __restrict__ Af, const float* __restrict__ Bf,
    float* __restrict__ out, int M, int N, int K)
{
    __shared__ char sm[32768];
    const int tid  = threadIdx.x;
    const int lane = tid & 63;
    const int w    = tid >> 6;
    const int bm = blockIdx.y, bn = blockIdx.x;
    const int wm = (w >> 1) * 64;
    const int wn = (w & 1) * 64;

    f32x4 acc[4][4] = {};
    const int sfetch = (tid & 3) ^ ((tid >> 3) & 3);
    const int rA = lane & 15;
    const int ca = (lane >> 4) ^ ((lane >> 1) & 3);
    const char* aP = sm +         (wm + rA) * 64 + ca * 16;
    const char* bP = sm + 16384 + (wn + rA) * 64 + ca * 16;

    for (int k0 = 0; k0 < K; k0 += 32) {
        __syncthreads();
#pragma unroll
        for (int c = 0; c < 4; ++c) {
            const bool isA = (c < 2);
            const int row = ((c & 1) << 6) + (tid >> 2);
            const float* src = (isA ? Af + (size_t)(bm * 128 + row) * K
                                    : Bf + (size_t)(bn * 128 + row) * K)
                               + k0 + ((tid & 3) << 3);
            f32x4 v0 = *(const f32x4*)src;
            f32x4 v1 = *(const f32x4*)(src + 4);
            float vv[8] = {v0.x, v0.y, v0.z, v0.w, v1.x, v1.y, v1.z, v1.w};
            bf16x8 h, l;
#pragma unroll
            for (int j = 0; j < 8; ++j) {
                unsigned short hb = f32_to_bf16_rtn(vv[j]);
                unsigned short lb = f32_to_bf16_rtn(vv[j] - bf16_bits_to_f32(hb));
                h[j] = (short)hb; l[j] = (short)lb;
            }
            const int g = row * 64 + sfetch * 16;
            *(bf16x8*)(sm + (isA ? 0 : 16384) + g) = h;
            *(bf16x8*)(sm + (isA ? 8192 : 24576) + g) = l;
        }
        __syncthreads();

        bf16x8 bh[4], bl[4];
#pragma unroll
        for (int j = 0; j < 4; ++j) {
            bh[j] = *(const bf16x8*)(bP + j * 1024);
            bl[j] = *(const bf16x8*)(bP + j * 1024 + 8192);
        }
#pragma unroll
        for (int i = 0; i < 4; ++i) {
            bf16x8 ah = *(const bf16x8*)(aP + i * 1024);
            bf16x8 al = *(const bf16x8*)(aP + i * 1024 + 8192);
#pragma unroll
            for (int j = 0; j < 4; ++j) {
                acc[i][j] = __builtin_amdgcn_mfma_f32_16x16x32_bf16(ah, bh[j], acc[i][j], 0, 0, 0);
                acc[i][j] = __builtin_amdgcn_mfma_f32_16x16x32_bf16(al, bh[j], acc[i][j], 0, 0, 0);
                acc[i][j] = __builtin_amdgcn_mfma_f32_16x16x32_bf16(ah, bl[j], acc[i][j], 0, 0, 0);
            }
        }
    }

    const int r0 = bm * 128 + wm + ((lane >> 4) << 2);
    const int c0 = bn * 128 + wn + rA;
#pragma unroll
    for (int i = 0; i < 4; ++i)
#pragma unroll
        for (int j = 0; j < 4; ++j)
#pragma unroll
            for (int r = 0; r < 4; ++r)
                out[(size_t)(r0 + i * 16 + r) * N + (c0 + j * 16)] = acc[i][j][r];
}

// ---------------------------------------------------------------------------
// Kernel 3: in-place row softmax, persistent blocks.
// 2048 blocks x 256 threads; each block processes 4 consecutive rows of 8192
// floats (8 f32x4 per thread per row). Row loop self-pipelines: NT stores of
// row j don't block the loads of row j+1 (no store->load waitcnt dependency).
// ---------------------------------------------------------------------------
__global__ __launch_bounds__(256) void softmax_rows_8192(float* __restrict__ d)
{
    const int tid = threadIdx.x;
    __shared__ float smax[4], ssum[4];

    for (int rr = 0; rr < 4; ++rr) {
        const size_t row = (size_t)blockIdx.x * 4 + rr;
        f32x4* p = (f32x4*)(d + row * 8192);
        f32x4 v[8];
        float m = -3.402823466e+38f;
#pragma unroll
        for (int i = 0; i < 8; ++i) {
            v[i] = p[tid + (i << 8)];
            m = fmaxf(m, fmaxf(fmaxf(v[i].x, v[i].y), fmaxf(v[i].z, v[i].w)));
        }
#pragma unroll
        for (int o = 32; o >= 1; o >>= 1) m = fmaxf(m, __shfl_xor(m, o));
        if ((tid & 63) == 0) smax[tid >> 6] = m;
        __syncthreads();
        m = fmaxf(fmaxf(smax[0], smax[1]), fmaxf(smax[2], smax[3]));

        float s = 0.f;
#pragma unroll
        for (int i = 0; i < 8; ++i) {
            v[i].x = __expf(v[i].x - m);
            v[i].y = __expf(v[i].y - m);
            v[i].z = __expf(v[i].z - m);
            v[i].w = __expf(v[i].w - m);
            s += (v[i].x + v[i].y) + (v[i].z + v[i].w);
        }
#pragma unroll
        for (int o = 32; o >= 1; o >>= 1) s += __shfl_xor(s, o);
        if ((tid & 63) == 0) ssum[tid >> 6] = s;
        __syncthreads();
        s = (ssum[0] + ssum[1]) + (ssum[2] + ssum[3]);
        const float r = 1.0f / s;
#pragma unroll
        for (int i = 0; i < 8; ++i) {
            v[i] *= r;
            __builtin_nontemporal_store(v[i], &p[tid + (i << 8)]);
        }
        __syncthreads();   // smax/ssum reused next row
    }
}

// ---------------------------------------------------------------------------
extern "C" void kernel_launch(void* const* d_in, const int* in_sizes, int n_in,
                              void* d_out, int out_size, void* d_ws, size_t ws_size,
                              hipStream_t stream)
{
    const float* A = (const float*)d_in[0];   // user_emb [M, K] fp32
    const float* B = (const float*)d_in[1];   // id_emb   [N, K] fp32
    float* out = (float*)d_out;               // [M, N] fp32
    const int K = 1024;
    const int M = in_sizes[0] / K;
    const int N = in_sizes[1] / K;
    const size_t elemsA = (size_t)M * K;
    const size_t elemsB = (size_t)N * K;
    const size_t need = 2 * (elemsA + elemsB) * sizeof(unsigned short);

    dim3 grid(N / 128, M / 128);
    const bool presplit = (ws_size >= need) && (M == N);

    if (presplit) {
        unsigned short* Ahi = (unsigned short*)d_ws;
        unsigned short* Alo = Ahi + elemsA;
        unsigned short* Bhi = Alo + elemsA;
        unsigned short* Blo = Bhi + elemsB;
        const int n4 = (int)(elemsA / 4);
        split_hi_lo<<<(n4 + 255) / 256, 256, 0, stream>>>(A, B, Ahi, Alo, Bhi, Blo, n4);
        gemm_presplit<<<grid, 256, 0, stream>>>(
            (const __hip_bfloat16*)Ahi, (const __hip_bfloat16*)Alo,
            (const __hip_bfloat16*)Bhi, (const __hip_bfloat16*)Blo,
            out, M, N, K);
    } else {
        gemm_fallback<<<grid, 256, 0, stream>>>(A, B, out, M, N, K);
    }
    softmax_rows_8192<<<M / 4, 256, 0, stream>>>(out);
}